// Round 2
// baseline (535.764 us; speedup 1.0000x reference)
//
#include <hip/hip_runtime.h>
#include <math.h>

#define C_DIM 256
#define N_EMB 8192
#define N_Z   8192
#define HWB   1024          // H*W per batch
#define MB    64            // z rows per block
#define NT    256           // emb cols per tile
#define KC    32            // k-chunk
#define NSPLIT 8            // codebook splits
#define ZQ_ELEMS (N_Z * C_DIM)

__device__ __forceinline__ float sqf(float x) { return __fmul_rn(x, x); }

// Exact replication of numpy pairwise summation of 256 squared elements:
// n=256 -> split 128+128; each 128: 8 accumulators r[j], i=8..120 step 8,
// combine ((r0+r1)+(r2+r3))+((r4+r5)+(r6+r7)); total = h0 + h1.
template <int STRIDE>
__device__ float pw_sumsq_256(const float* __restrict__ a) {
  float h[2];
#pragma unroll
  for (int hh = 0; hh < 2; ++hh) {
    const float* p = a + hh * 128 * STRIDE;
    float r0 = sqf(p[0 * STRIDE]), r1 = sqf(p[1 * STRIDE]);
    float r2 = sqf(p[2 * STRIDE]), r3 = sqf(p[3 * STRIDE]);
    float r4 = sqf(p[4 * STRIDE]), r5 = sqf(p[5 * STRIDE]);
    float r6 = sqf(p[6 * STRIDE]), r7 = sqf(p[7 * STRIDE]);
    for (int i = 8; i < 128; i += 8) {
      r0 = __fadd_rn(r0, sqf(p[(i + 0) * STRIDE]));
      r1 = __fadd_rn(r1, sqf(p[(i + 1) * STRIDE]));
      r2 = __fadd_rn(r2, sqf(p[(i + 2) * STRIDE]));
      r3 = __fadd_rn(r3, sqf(p[(i + 3) * STRIDE]));
      r4 = __fadd_rn(r4, sqf(p[(i + 4) * STRIDE]));
      r5 = __fadd_rn(r5, sqf(p[(i + 5) * STRIDE]));
      r6 = __fadd_rn(r6, sqf(p[(i + 6) * STRIDE]));
      r7 = __fadd_rn(r7, sqf(p[(i + 7) * STRIDE]));
    }
    h[hh] = __fadd_rn(__fadd_rn(__fadd_rn(r0, r1), __fadd_rn(r2, r3)),
                      __fadd_rn(__fadd_rn(r4, r5), __fadd_rn(r6, r7)));
  }
  return __fadd_rn(h[0], h[1]);
}

// blocks 0..31: e2 rows; blocks 32..63: z2 rows
__global__ void vq_norms(const float* __restrict__ hid, const float* __restrict__ emb,
                         float* __restrict__ z2, float* __restrict__ e2) {
  int t = threadIdx.x, b = blockIdx.x;
  if (b < 32) {
    int r = b * 256 + t;
    e2[r] = pw_sumsq_256<1>(emb + (size_t)r * C_DIM);
  } else {
    int n = (b - 32) * 256 + t;
    int bb = n >> 10, hw = n & 1023;
    z2[n] = pw_sumsq_256<HWB>(hid + (size_t)bb * C_DIM * HWB + hw);
  }
}

// Distance + per-split argmin. Block: 64 z-rows x (N_EMB/NSPLIT) emb cols.
// 256 threads: rg = t>>5 (8 row groups), l = t&31 (col lanes).
// Per-thread 8x8 register tile: rows rg + rr*8, cols l + jj*32 (+ tile*NT).
// LDS layout: row-major, 32 floats/row (128 B, no pad); the 16B slot s of row r
// is stored at physical slot (s ^ (r&7)) -> every b128 read/write has each
// consecutive-8-lane group covering all 32 banks (conflict-free).
__global__ __launch_bounds__(256, 4) void vq_dist(
    const float* __restrict__ hid, const float* __restrict__ emb,
    const float* __restrict__ z2g, const float* __restrict__ e2g,
    float* __restrict__ cd, int* __restrict__ ci) {
  __shared__ float zl[MB * KC];    //  8 KB
  __shared__ float el[NT * KC];    // 32 KB
  int t = threadIdx.x;
  int mb = blockIdx.x >> 3;        // 0..127
  int ns = blockIdx.x & (NSPLIT - 1);
  int n0z = mb * MB;
  int bb = n0z >> 10, hw0 = n0z & 1023;
  const float* hb = hid + (size_t)bb * C_DIM * HWB + hw0;

  int rg = t >> 5, l = t & 31;
  float z2r[8];
#pragma unroll
  for (int rr = 0; rr < 8; ++rr) z2r[rr] = z2g[n0z + rg + rr * 8];

  float best[8];
  int bidx[8];
#pragma unroll
  for (int rr = 0; rr < 8; ++rr) { best[rr] = INFINITY; bidx[rr] = 0; }

  const int n0e_base = ns * (N_EMB / NSPLIT);
  // staging index helpers
  const int zs_r = t & 63, zs_sg = (t >> 6) * 2;    // z: row, 2 slot-groups
  const int es_k4 = t & 7, es_n0 = t >> 3;          // e: slot, base row
  const int es_soff = ((es_k4 ^ (es_n0 & 7)) << 2); // e store slot offset (floats)
  const int exor = l & 7;                           // e read slot xor

  for (int tile = 0; tile < (N_EMB / NSPLIT) / NT; ++tile) {
    int ne0 = n0e_base + tile * NT;
    float acc[8][8];
#pragma unroll
    for (int i = 0; i < 8; ++i)
#pragma unroll
      for (int j = 0; j < 8; ++j) acc[i][j] = 0.f;

    for (int kc = 0; kc < C_DIM / KC; ++kc) {
      __syncthreads();   // prior compute done before restaging
      // stage z chunk: zl[r][s] = z[n0z+r][kc*32+s*4..+3], pack 4 strided reads
#pragma unroll
      for (int p = 0; p < 2; ++p) {
        int s = zs_sg + p;
        const float* g = hb + (size_t)(kc * KC + s * 4) * HWB + zs_r;
        float4 v = make_float4(g[0], g[HWB], g[2 * HWB], g[3 * HWB]);
        *(float4*)(zl + zs_r * KC + ((s ^ (zs_r & 7)) << 2)) = v;
      }
      // stage e chunk: el[nn][k4] from row-major emb, b128 both sides
#pragma unroll
      for (int p = 0; p < 8; ++p) {
        int nn = es_n0 + p * 32;
        float4 v = *(const float4*)(emb + (size_t)(ne0 + nn) * C_DIM + kc * KC + es_k4 * 4);
        *(float4*)(el + nn * KC + es_soff) = v;
      }
      __syncthreads();
#pragma unroll
      for (int k4 = 0; k4 < KC / 4; ++k4) {
        float4 zv[8], ev[8];
        int zo = ((k4 ^ rg) << 2);
        int eo = ((k4 ^ exor) << 2);
#pragma unroll
        for (int rr = 0; rr < 8; ++rr)
          zv[rr] = *(const float4*)(zl + (rg + rr * 8) * KC + zo);
#pragma unroll
        for (int jj = 0; jj < 8; ++jj)
          ev[jj] = *(const float4*)(el + (l + jj * 32) * KC + eo);
#pragma unroll
        for (int rr = 0; rr < 8; ++rr)
#pragma unroll
          for (int jj = 0; jj < 8; ++jj) {
            float a = acc[rr][jj];
            a = fmaf(zv[rr].x, ev[jj].x, a);
            a = fmaf(zv[rr].y, ev[jj].y, a);
            a = fmaf(zv[rr].z, ev[jj].z, a);
            a = fmaf(zv[rr].w, ev[jj].w, a);
            acc[rr][jj] = a;
          }
      }
    }
    // scores: numpy expr fl(fl(z2+e2) - fl(2*dot)); ascending index order
#pragma unroll
    for (int jj = 0; jj < 8; ++jj) {
      int ce = ne0 + l + jj * 32;
      float e2v = e2g[ce];
#pragma unroll
      for (int rr = 0; rr < 8; ++rr) {
        float s1 = __fadd_rn(z2r[rr], e2v);
        float s = __fsub_rn(s1, __fmul_rn(2.0f, acc[rr][jj]));
        if (s < best[rr]) { best[rr] = s; bidx[rr] = ce; }
      }
    }
  }
  // reduce across the 32 lanes of each row group (xor <=16 stays in-half)
#pragma unroll
  for (int rr = 0; rr < 8; ++rr) {
    float b = best[rr];
    int i = bidx[rr];
#pragma unroll
    for (int m = 16; m >= 1; m >>= 1) {
      float ob = __shfl_xor(b, m);
      int oi = __shfl_xor(i, m);
      if (ob < b || (ob == b && oi < i)) { b = ob; i = oi; }
    }
    if (l == 0) {
      cd[ns * N_Z + n0z + rg + rr * 8] = b;
      ci[ns * N_Z + n0z + rg + rr * 8] = i;
    }
  }
}

// merge NSPLIT candidates per row, write indices (as float) and gather z_q
__global__ void vq_out(const float* __restrict__ emb, const float* __restrict__ cd,
                       const int* __restrict__ ci, float* __restrict__ out) {
  __shared__ int sidx[32];
  int t = threadIdx.x;
  int n0 = blockIdx.x * 32;
  if (t < 32) {
    int n = n0 + t;
    float b = INFINITY;
    int bi = 0;
    for (int ns = 0; ns < NSPLIT; ++ns) {        // ascending split = ascending idx
      float d = cd[ns * N_Z + n];
      int i = ci[ns * N_Z + n];
      if (d < b || (d == b && i < bi)) { b = d; bi = i; }
    }
    sidx[t] = bi;
    out[ZQ_ELEMS + n] = (float)bi;
  }
  __syncthreads();
  int bb = n0 >> 10, hw0 = n0 & 1023;
  int nl = t & 31, cg = t >> 5;   // 8 col groups of 4
#pragma unroll
  for (int p = 0; p < 8; ++p) {
    int c0 = cg * 4 + p * 32;
    float4 v = *(const float4*)(emb + (size_t)sidx[nl] * C_DIM + c0);
    out[((size_t)bb * C_DIM + c0 + 0) * HWB + hw0 + nl] = v.x;
    out[((size_t)bb * C_DIM + c0 + 1) * HWB + hw0 + nl] = v.y;
    out[((size_t)bb * C_DIM + c0 + 2) * HWB + hw0 + nl] = v.z;
    out[((size_t)bb * C_DIM + c0 + 3) * HWB + hw0 + nl] = v.w;
  }
}

extern "C" void kernel_launch(void* const* d_in, const int* in_sizes, int n_in,
                              void* d_out, int out_size, void* d_ws, size_t ws_size,
                              hipStream_t stream) {
  const float* hid = (const float*)d_in[0];
  const float* emb = (const float*)d_in[1];
  float* out = (float*)d_out;

  float* z2 = (float*)d_ws;                 // 8192
  float* e2 = z2 + N_Z;                     // 8192
  float* cd = e2 + N_EMB;                   // NSPLIT*8192
  int* ci = (int*)(cd + (size_t)NSPLIT * N_Z);  // NSPLIT*8192

  vq_norms<<<64, 256, 0, stream>>>(hid, emb, z2, e2);
  vq_dist<<<(N_Z / MB) * NSPLIT, 256, 0, stream>>>(hid, emb, z2, e2, cd, ci);
  vq_out<<<N_Z / 32, 256, 0, stream>>>(emb, cd, ci, out);
}

// Round 3
// 517.162 us; speedup vs baseline: 1.0360x; 1.0360x over previous
//
#include <hip/hip_runtime.h>
#include <math.h>

#define C_DIM 256
#define N_EMB 8192
#define N_Z   8192
#define HWB   1024          // H*W per batch
#define MB    64            // z rows per vq_dist block (4 waves x 16)
#define RPW   16            // z rows per wave
#define NT    128           // emb cols per tile
#define KC    32            // k-chunk
#define NSPLIT 8            // codebook splits (ns = bid&7 -> XCD-local e split)
#define ZQ_ELEMS (N_Z * C_DIM)

__device__ __forceinline__ float sqf(float x) { return __fmul_rn(x, x); }

// Exact replication of numpy pairwise summation of 256 squared elements:
// n=256 -> split 128+128; each 128: 8 accumulators, i=8..120 step 8,
// combine ((r0+r1)+(r2+r3))+((r4+r5)+(r6+r7)); total = h0 + h1.
template <int STRIDE>
__device__ float pw_sumsq_256(const float* __restrict__ a) {
  float h[2];
#pragma unroll
  for (int hh = 0; hh < 2; ++hh) {
    const float* p = a + hh * 128 * STRIDE;
    float r0 = sqf(p[0 * STRIDE]), r1 = sqf(p[1 * STRIDE]);
    float r2 = sqf(p[2 * STRIDE]), r3 = sqf(p[3 * STRIDE]);
    float r4 = sqf(p[4 * STRIDE]), r5 = sqf(p[5 * STRIDE]);
    float r6 = sqf(p[6 * STRIDE]), r7 = sqf(p[7 * STRIDE]);
    for (int i = 8; i < 128; i += 8) {
      r0 = __fadd_rn(r0, sqf(p[(i + 0) * STRIDE]));
      r1 = __fadd_rn(r1, sqf(p[(i + 1) * STRIDE]));
      r2 = __fadd_rn(r2, sqf(p[(i + 2) * STRIDE]));
      r3 = __fadd_rn(r3, sqf(p[(i + 3) * STRIDE]));
      r4 = __fadd_rn(r4, sqf(p[(i + 4) * STRIDE]));
      r5 = __fadd_rn(r5, sqf(p[(i + 5) * STRIDE]));
      r6 = __fadd_rn(r6, sqf(p[(i + 6) * STRIDE]));
      r7 = __fadd_rn(r7, sqf(p[(i + 7) * STRIDE]));
    }
    h[hh] = __fadd_rn(__fadd_rn(__fadd_rn(r0, r1), __fadd_rn(r2, r3)),
                      __fadd_rn(__fadd_rn(r4, r5), __fadd_rn(r6, r7)));
  }
  return __fadd_rn(h[0], h[1]);
}

// Transpose hid [b][c][hw] -> zt [n=b*1024+hw][c]. 32x32 tiles via LDS.
__global__ void vq_tr(const float* __restrict__ hid, float* __restrict__ zt) {
  __shared__ float tl[32][33];
  int t = threadIdx.x;
  int tx = t & 31, ty = t >> 5;               // 32 x 8
  int bb = blockIdx.x >> 8;                   // 0..7
  int r = blockIdx.x & 255;
  int cT = r >> 5, hwT = r & 31;              // 8 c-tiles x 32 hw-tiles
#pragma unroll
  for (int p = 0; p < 4; ++p)
    tl[ty + p * 8][tx] =
        hid[((size_t)bb * C_DIM + cT * 32 + ty + p * 8) * HWB + hwT * 32 + tx];
  __syncthreads();
#pragma unroll
  for (int p = 0; p < 4; ++p)
    zt[((size_t)bb * HWB + hwT * 32 + ty + p * 8) * C_DIM + cT * 32 + tx] =
        tl[tx][ty + p * 8];
}

// blocks 0..31: e2 rows; blocks 32..63: z2 rows (from zt, stride 1, same order)
__global__ void vq_norms(const float* __restrict__ zt, const float* __restrict__ emb,
                         float* __restrict__ z2, float* __restrict__ e2) {
  int t = threadIdx.x, b = blockIdx.x;
  if (b < 32) {
    int r = b * 256 + t;
    e2[r] = pw_sumsq_256<1>(emb + (size_t)r * C_DIM);
  } else {
    int n = (b - 32) * 256 + t;
    z2[n] = pw_sumsq_256<1>(zt + (size_t)n * C_DIM);
  }
}

// Distance + per-split argmin.
// Block: 4 waves x 16 z-rows = 64 rows; 64 lanes x 2 cols = NT=128 e-cols/tile.
// z operands are wave-uniform loads straight from global zt (no LDS, no conflicts).
// e tile in LDS (16 KB), 16B-slot XOR swizzle (slot ^ (row&7)) both sides.
__global__ __launch_bounds__(256, 4) void vq_dist(
    const float* __restrict__ zt, const float* __restrict__ emb,
    const float* __restrict__ z2g, const float* __restrict__ e2g,
    float* __restrict__ cd, int* __restrict__ ci) {
  __shared__ float el[NT * KC];   // 16 KB
  int t = threadIdx.x;
  int mb = blockIdx.x >> 3;                    // 0..127
  int ns = blockIdx.x & (NSPLIT - 1);          // XCD-local split
  int n0z = mb * MB;
  int l = t & 63;
  int wu = __builtin_amdgcn_readfirstlane(t >> 6);   // wave id 0..3 (uniform)
  const float* ztw = zt + (size_t)(n0z + wu * RPW) * C_DIM;

  float z2r[RPW];
#pragma unroll
  for (int rr = 0; rr < RPW; ++rr) z2r[rr] = z2g[n0z + wu * RPW + rr];

  float best[RPW];
  int bidx[RPW];
#pragma unroll
  for (int rr = 0; rr < RPW; ++rr) { best[rr] = INFINITY; bidx[rr] = 0; }

  const int es_k4 = t & 7, es_n0 = t >> 3;            // e-stage: slot, base row
  const int es_soff = ((es_k4 ^ (es_n0 & 7)) << 2);   // swizzled slot offset
  const int exor = l & 7;                             // e-read swizzle

  for (int tile = 0; tile < (N_EMB / NSPLIT) / NT; ++tile) {   // 8 tiles
    int ne0 = ns * (N_EMB / NSPLIT) + tile * NT;
    float acc[RPW][2];
#pragma unroll
    for (int rr = 0; rr < RPW; ++rr) { acc[rr][0] = 0.f; acc[rr][1] = 0.f; }

    for (int kc = 0; kc < C_DIM / KC; ++kc) {
      __syncthreads();
      // stage e chunk: 128 rows x 32 k, 4 b128 per thread, swizzled
#pragma unroll
      for (int p = 0; p < 4; ++p) {
        int nn = es_n0 + p * 32;
        float4 v = *(const float4*)(emb + (size_t)(ne0 + nn) * C_DIM + kc * KC + es_k4 * 4);
        *(float4*)(el + nn * KC + es_soff) = v;
      }
      __syncthreads();
      const float* ztk = ztw + kc * KC;
#pragma unroll
      for (int k4 = 0; k4 < KC / 4; ++k4) {
        int eo = ((k4 ^ exor) << 2);
        float4 ev0 = *(const float4*)(el + l * KC + eo);
        float4 ev1 = *(const float4*)(el + (l + 64) * KC + eo);
#pragma unroll
        for (int rr = 0; rr < RPW; ++rr) {
          float4 zv = *(const float4*)(ztk + rr * C_DIM + k4 * 4);  // wave-uniform
          float a0 = acc[rr][0], a1 = acc[rr][1];
          a0 = fmaf(zv.x, ev0.x, a0); a1 = fmaf(zv.x, ev1.x, a1);
          a0 = fmaf(zv.y, ev0.y, a0); a1 = fmaf(zv.y, ev1.y, a1);
          a0 = fmaf(zv.z, ev0.z, a0); a1 = fmaf(zv.z, ev1.z, a1);
          a0 = fmaf(zv.w, ev0.w, a0); a1 = fmaf(zv.w, ev1.w, a1);
          acc[rr][0] = a0; acc[rr][1] = a1;
        }
      }
    }
    // scores: numpy expr fl(fl(z2+e2) - fl(2*dot)); ascending index order
#pragma unroll
    for (int jj = 0; jj < 2; ++jj) {
      int ce = ne0 + l + jj * 64;
      float e2v = e2g[ce];
#pragma unroll
      for (int rr = 0; rr < RPW; ++rr) {
        float s1 = __fadd_rn(z2r[rr], e2v);
        float s = __fsub_rn(s1, __fmul_rn(2.0f, acc[rr][jj]));
        if (s < best[rr]) { best[rr] = s; bidx[rr] = ce; }
      }
    }
  }
  // reduce across 64 lanes; ties -> lowest index
#pragma unroll
  for (int rr = 0; rr < RPW; ++rr) {
    float b = best[rr];
    int i = bidx[rr];
#pragma unroll
    for (int m = 32; m >= 1; m >>= 1) {
      float ob = __shfl_xor(b, m, 64);
      int oi = __shfl_xor(i, m, 64);
      if (ob < b || (ob == b && oi < i)) { b = ob; i = oi; }
    }
    if (l == 0) {
      cd[ns * N_Z + n0z + wu * RPW + rr] = b;
      ci[ns * N_Z + n0z + wu * RPW + rr] = i;
    }
  }
}

// merge NSPLIT candidates per row, write indices (as float) and gather z_q
__global__ void vq_out(const float* __restrict__ emb, const float* __restrict__ cd,
                       const int* __restrict__ ci, float* __restrict__ out) {
  __shared__ int sidx[32];
  int t = threadIdx.x;
  int n0 = blockIdx.x * 32;
  if (t < 32) {
    int n = n0 + t;
    float b = INFINITY;
    int bi = 0;
    for (int ns = 0; ns < NSPLIT; ++ns) {        // ascending split = ascending idx
      float d = cd[ns * N_Z + n];
      int i = ci[ns * N_Z + n];
      if (d < b || (d == b && i < bi)) { b = d; bi = i; }
    }
    sidx[t] = bi;
    out[ZQ_ELEMS + n] = (float)bi;
  }
  __syncthreads();
  int bb = n0 >> 10, hw0 = n0 & 1023;
  int nl = t & 31, cg = t >> 5;   // 8 col groups of 4
#pragma unroll
  for (int p = 0; p < 8; ++p) {
    int c0 = cg * 4 + p * 32;
    float4 v = *(const float4*)(emb + (size_t)sidx[nl] * C_DIM + c0);
    out[((size_t)bb * C_DIM + c0 + 0) * HWB + hw0 + nl] = v.x;
    out[((size_t)bb * C_DIM + c0 + 1) * HWB + hw0 + nl] = v.y;
    out[((size_t)bb * C_DIM + c0 + 2) * HWB + hw0 + nl] = v.z;
    out[((size_t)bb * C_DIM + c0 + 3) * HWB + hw0 + nl] = v.w;
  }
}

extern "C" void kernel_launch(void* const* d_in, const int* in_sizes, int n_in,
                              void* d_out, int out_size, void* d_ws, size_t ws_size,
                              hipStream_t stream) {
  const float* hid = (const float*)d_in[0];
  const float* emb = (const float*)d_in[1];
  float* out = (float*)d_out;

  float* zt = (float*)d_ws;                       // 8192*256 = 2,097,152 floats (8 MB)
  float* z2 = zt + (size_t)N_Z * C_DIM;           // 8192
  float* e2 = z2 + N_Z;                           // 8192
  float* cd = e2 + N_EMB;                         // NSPLIT*8192
  int* ci = (int*)(cd + (size_t)NSPLIT * N_Z);    // NSPLIT*8192

  vq_tr<<<2048, 256, 0, stream>>>(hid, zt);
  vq_norms<<<64, 256, 0, stream>>>(zt, emb, z2, e2);
  vq_dist<<<(N_Z / MB) * NSPLIT, 256, 0, stream>>>(zt, emb, z2, e2, cd, ci);
  vq_out<<<N_Z / 32, 256, 0, stream>>>(emb, cd, ci, out);
}

// Round 5
// 444.204 us; speedup vs baseline: 1.2061x; 1.1642x over previous
//
#include <hip/hip_runtime.h>
#include <hip/hip_bf16.h>
#include <math.h>

#define C_DIM 256
#define N_EMB 8192
#define N_Z   8192
#define HWB   1024
#define MBLK  128                 // z rows per filter block
#define NSPLIT 8                  // codebook splits (ns = bid&7 -> XCD-local)
#define SPLITC (N_EMB / NSPLIT)   // 1024 cols per split
#define NT    256                 // e cols per tile
#define NTILES (SPLITC / NT)      // 4
#define KC    64                  // k chunk (bf16)
#define CK    44                  // candidate slots per row
#define EPS   1.1e-3f             // >= 2*hard bound on |s_exact - s_approx| (~7.8e-4)
#define ZQ_ELEMS (N_Z * C_DIM)

typedef __attribute__((ext_vector_type(8))) short bf16x8;
typedef __attribute__((ext_vector_type(4))) float f32x4;
typedef unsigned short u16;
typedef unsigned int u32;

__device__ __forceinline__ float sqf(float x) { return __fmul_rn(x, x); }

__device__ __forceinline__ u16 f2bf(float v) {
  __hip_bfloat16 h = __float2bfloat16(v);
  u16 r; __builtin_memcpy(&r, &h, 2); return r;
}

// Exact replication of numpy pairwise summation of 256 squared elements.
template <int STRIDE>
__device__ float pw_sumsq_256(const float* __restrict__ a) {
  float h[2];
#pragma unroll
  for (int hh = 0; hh < 2; ++hh) {
    const float* p = a + hh * 128 * STRIDE;
    float r0 = sqf(p[0 * STRIDE]), r1 = sqf(p[1 * STRIDE]);
    float r2 = sqf(p[2 * STRIDE]), r3 = sqf(p[3 * STRIDE]);
    float r4 = sqf(p[4 * STRIDE]), r5 = sqf(p[5 * STRIDE]);
    float r6 = sqf(p[6 * STRIDE]), r7 = sqf(p[7 * STRIDE]);
    for (int i = 8; i < 128; i += 8) {
      r0 = __fadd_rn(r0, sqf(p[(i + 0) * STRIDE]));
      r1 = __fadd_rn(r1, sqf(p[(i + 1) * STRIDE]));
      r2 = __fadd_rn(r2, sqf(p[(i + 2) * STRIDE]));
      r3 = __fadd_rn(r3, sqf(p[(i + 3) * STRIDE]));
      r4 = __fadd_rn(r4, sqf(p[(i + 4) * STRIDE]));
      r5 = __fadd_rn(r5, sqf(p[(i + 5) * STRIDE]));
      r6 = __fadd_rn(r6, sqf(p[(i + 6) * STRIDE]));
      r7 = __fadd_rn(r7, sqf(p[(i + 7) * STRIDE]));
    }
    h[hh] = __fadd_rn(__fadd_rn(__fadd_rn(r0, r1), __fadd_rn(r2, r3)),
                      __fadd_rn(__fadd_rn(r4, r5), __fadd_rn(r6, r7)));
  }
  return __fadd_rn(h[0], h[1]);
}

// exact sequential dot (k = 0..255 ascending, xyzw) -- identical op order to
// the verified exact path of rounds 1-3.
__device__ __forceinline__ float exact_score(const float* __restrict__ zr,
                                             const float* __restrict__ er,
                                             float z2v, float e2v) {
  float d = 0.f;
  for (int k4 = 0; k4 < 64; ++k4) {
    float4 a4 = *(const float4*)(zr + k4 * 4);
    float4 b4 = *(const float4*)(er + k4 * 4);
    d = fmaf(a4.x, b4.x, d); d = fmaf(a4.y, b4.y, d);
    d = fmaf(a4.z, b4.z, d); d = fmaf(a4.w, b4.w, d);
  }
  return __fsub_rn(__fadd_rn(z2v, e2v), __fmul_rn(2.f, d));
}

// Transpose hid [b][c][hw] -> zt fp32 [n][c] and zbf bf16 [n][c].
__global__ void vq_tr(const float* __restrict__ hid, float* __restrict__ zt,
                      u16* __restrict__ zbf) {
  __shared__ float tl[32][33];
  int t = threadIdx.x;
  int tx = t & 31, ty = t >> 5;
  int bb = blockIdx.x >> 8;
  int r = blockIdx.x & 255;
  int cT = r >> 5, hwT = r & 31;
#pragma unroll
  for (int p = 0; p < 4; ++p)
    tl[ty + p * 8][tx] =
        hid[((size_t)bb * C_DIM + cT * 32 + ty + p * 8) * HWB + hwT * 32 + tx];
  __syncthreads();
#pragma unroll
  for (int p = 0; p < 4; ++p) {
    float v = tl[tx][ty + p * 8];
    size_t oi = ((size_t)bb * HWB + hwT * 32 + ty + p * 8) * C_DIM + cT * 32 + tx;
    zt[oi] = v;
    zbf[oi] = f2bf(v);
  }
}

// blocks 0..31: e2 + ebf; blocks 32..63: z2 (from zt)
__global__ void vq_norms(const float* __restrict__ zt, const float* __restrict__ emb,
                         float* __restrict__ z2, float* __restrict__ e2,
                         u16* __restrict__ ebf) {
  int t = threadIdx.x, b = blockIdx.x;
  if (b < 32) {
    int r = b * 256 + t;
    e2[r] = pw_sumsq_256<1>(emb + (size_t)r * C_DIM);
    for (int k4 = 0; k4 < 64; ++k4) {
      float4 v = *(const float4*)(emb + (size_t)r * C_DIM + k4 * 4);
      ushort4 o;
      o.x = f2bf(v.x); o.y = f2bf(v.y); o.z = f2bf(v.z); o.w = f2bf(v.w);
      *(ushort4*)(ebf + (size_t)r * C_DIM + k4 * 4) = o;
    }
  } else {
    int n = (b - 32) * 256 + t;
    z2[n] = pw_sumsq_256<1>(zt + (size_t)n * C_DIM);
  }
}

// MFMA bf16 filter + exact rescreen.
// Block: 256 thr = 4 waves as 2x2 over a 128-row x 256-col tile (wave: 64x128).
// LDS tiles row-major 64 bf16/row (8 x 16B slots), slot ^= (row&7) swizzle.
// Approx s' tracks per-row running min; cols within EPS of it go to per-row
// candidate lists; candidates are re-scored EXACTLY and argmin'd (lowest-index
// tie-break). Rows whose list overflowed (statistically never) get a
// block-wide exact scan of the whole split -> correctness is unconditional.
__global__ __launch_bounds__(256, 2) void vq_filter(
    const u16* __restrict__ zbf, const u16* __restrict__ ebf,
    const float* __restrict__ zt, const float* __restrict__ emb,
    const float* __restrict__ z2g, const float* __restrict__ e2g,
    float* __restrict__ cd, int* __restrict__ ci) {
  __shared__ u16 zl[MBLK * KC];       // 16 KB
  __shared__ u16 el[NT * KC];         // 32 KB
  __shared__ u16 rcol[MBLK * CK];     // 11 KB
  __shared__ int rcnt[MBLK];
  __shared__ int ovfr[16];
  __shared__ int novf;
  __shared__ float wbs[4];
  __shared__ int wis[4];

  int t = threadIdx.x;
  int mb = blockIdx.x >> 3;
  int ns = blockIdx.x & 7;
  int n0z = mb * MBLK;
  int l = t & 63;
  int w = t >> 6;
  int wr = w >> 1, wc = w & 1;

  if (t < MBLK) rcnt[t] = 0;
  if (t == 0) novf = 0;

  float z2r[4][4];
#pragma unroll
  for (int rf = 0; rf < 4; ++rf)
#pragma unroll
    for (int r = 0; r < 4; ++r)
      z2r[rf][r] = z2g[n0z + wr * 64 + rf * 16 + (l >> 4) * 4 + r];

  float mp[4][4];
#pragma unroll
  for (int rf = 0; rf < 4; ++rf)
#pragma unroll
    for (int r = 0; r < 4; ++r) mp[rf][r] = INFINITY;

  const f32x4 vzero = {0.f, 0.f, 0.f, 0.f};

  for (int tile = 0; tile < NTILES; ++tile) {
    int ne0 = ns * SPLITC + tile * NT;
    f32x4 acc[4][8];
#pragma unroll
    for (int rf = 0; rf < 4; ++rf)
#pragma unroll
      for (int cf = 0; cf < 8; ++cf) acc[rf][cf] = vzero;

    for (int kc = 0; kc < C_DIM; kc += KC) {
      __syncthreads();
      // stage z chunk 128x64
#pragma unroll
      for (int p = 0; p < 4; ++p) {
        int o = t + p * 256;
        int row = o >> 3, slot = o & 7;
        uint4 v = *(const uint4*)(zbf + (size_t)(n0z + row) * C_DIM + kc + slot * 8);
        *(uint4*)(zl + row * KC + ((slot ^ (row & 7)) << 3)) = v;
      }
      // stage e chunk 256x64
#pragma unroll
      for (int p = 0; p < 8; ++p) {
        int o = t + p * 256;
        int row = o >> 3, slot = o & 7;
        uint4 v = *(const uint4*)(ebf + (size_t)(ne0 + row) * C_DIM + kc + slot * 8);
        *(uint4*)(el + row * KC + ((slot ^ (row & 7)) << 3)) = v;
      }
      __syncthreads();
#pragma unroll
      for (int ks = 0; ks < 2; ++ks) {
        int so = ((ks * 4 + (l >> 4)) ^ (l & 7)) << 3;
        bf16x8 a[4];
#pragma unroll
        for (int rf = 0; rf < 4; ++rf)
          a[rf] = *(const bf16x8*)(zl + (wr * 64 + rf * 16 + (l & 15)) * KC + so);
#pragma unroll
        for (int cf = 0; cf < 8; ++cf) {
          bf16x8 bfr = *(const bf16x8*)(el + (wc * 128 + cf * 16 + (l & 15)) * KC + so);
#pragma unroll
          for (int rf = 0; rf < 4; ++rf)
            acc[rf][cf] = __builtin_amdgcn_mfma_f32_16x16x32_bf16(a[rf], bfr, acc[rf][cf], 0, 0, 0);
        }
      }
    }
    // epilogue: approx scores, row minima, per-row candidate appends
    float e2s[8];
#pragma unroll
    for (int cf = 0; cf < 8; ++cf)
      e2s[cf] = e2g[ne0 + wc * 128 + cf * 16 + (l & 15)];
#pragma unroll
    for (int rf = 0; rf < 4; ++rf) {
#pragma unroll
      for (int r = 0; r < 4; ++r) {
        float mn = INFINITY;
#pragma unroll
        for (int cf = 0; cf < 8; ++cf) {
          float s = fmaf(-2.f, acc[rf][cf][r], z2r[rf][r] + e2s[cf]);
          mn = fminf(mn, s);
        }
#pragma unroll
        for (int m = 1; m < 16; m <<= 1)
          mn = fminf(mn, __shfl_xor(mn, m, 64));
        mp[rf][r] = fminf(mp[rf][r], mn);
        float thr = mp[rf][r] + EPS;
        int rowl = wr * 64 + rf * 16 + (l >> 4) * 4 + r;
#pragma unroll
        for (int cf = 0; cf < 8; ++cf) {
          float s = fmaf(-2.f, acc[rf][cf][r], z2r[rf][r] + e2s[cf]);
          if (s <= thr) {
            int pos = atomicAdd(&rcnt[rowl], 1);
            if (pos < CK)
              rcol[rowl * CK + pos] = (u16)(ne0 + wc * 128 + cf * 16 + (l & 15));
          }
        }
      }
    }
  }
  __syncthreads();

  // exact rescreen: 2 threads per row, strided over that row's candidates
  {
    int row = t >> 1;
    int cnt = rcnt[row];
    float b = INFINITY; int bi = N_EMB;
    if (cnt <= CK) {
      const float* zr = zt + (size_t)(n0z + row) * C_DIM;
      float z2v = z2g[n0z + row];
      for (int p2 = (t & 1); p2 < cnt; p2 += 2) {
        int col = rcol[row * CK + p2];
        float s = exact_score(zr, emb + (size_t)col * C_DIM, z2v, e2g[col]);
        if (s < b || (s == b && col < bi)) { b = s; bi = col; }
      }
    }
    float ob = __shfl_xor(b, 1, 64);
    int oi2 = __shfl_xor(bi, 1, 64);
    if (ob < b || (ob == b && oi2 < bi)) { b = ob; bi = oi2; }
    if ((t & 1) == 0 && cnt <= CK) {
      cd[ns * N_Z + n0z + row] = b;
      ci[ns * N_Z + n0z + row] = bi;
    }
  }

  // overflow fallback: exact scan of the full split for any overflowed row
  if (t < MBLK && rcnt[t] > CK) {
    int p = atomicAdd(&novf, 1);
    if (p < 16) ovfr[p] = t;
  }
  __syncthreads();
  int no = min(novf, 16);
  for (int oi = 0; oi < no; ++oi) {
    int row = ovfr[oi];
    const float* zr = zt + (size_t)(n0z + row) * C_DIM;
    float z2v = z2g[n0z + row];
    float b = INFINITY; int bi = N_EMB;
    for (int q = 0; q < 4; ++q) {
      int col = ns * SPLITC + t * 4 + q;
      float s = exact_score(zr, emb + (size_t)col * C_DIM, z2v, e2g[col]);
      if (s < b || (s == b && col < bi)) { b = s; bi = col; }
    }
#pragma unroll
    for (int m = 1; m <= 32; m <<= 1) {
      float ob = __shfl_xor(b, m, 64);
      int oi2 = __shfl_xor(bi, m, 64);
      if (ob < b || (ob == b && oi2 < bi)) { b = ob; bi = oi2; }
    }
    if (l == 0) { wbs[w] = b; wis[w] = bi; }
    __syncthreads();
    if (t == 0) {
      for (int w2 = 1; w2 < 4; ++w2)
        if (wbs[w2] < b || (wbs[w2] == b && wis[w2] < bi)) { b = wbs[w2]; bi = wis[w2]; }
      cd[ns * N_Z + n0z + row] = b;
      ci[ns * N_Z + n0z + row] = bi;
    }
    __syncthreads();
  }
}

// merge NSPLIT candidates per row, write indices (as float) and gather z_q
__global__ void vq_out(const float* __restrict__ emb, const float* __restrict__ cd,
                       const int* __restrict__ ci, float* __restrict__ out) {
  __shared__ int sidx[32];
  int t = threadIdx.x;
  int n0 = blockIdx.x * 32;
  if (t < 32) {
    int n = n0 + t;
    float b = INFINITY;
    int bi = 0;
    for (int ns = 0; ns < NSPLIT; ++ns) {        // ascending split = ascending idx
      float d = cd[ns * N_Z + n];
      int i = ci[ns * N_Z + n];
      if (d < b || (d == b && i < bi)) { b = d; bi = i; }
    }
    sidx[t] = bi;
    out[ZQ_ELEMS + n] = (float)bi;
  }
  __syncthreads();
  int bb = n0 >> 10, hw0 = n0 & 1023;
  int nl = t & 31, cg = t >> 5;
#pragma unroll
  for (int p = 0; p < 8; ++p) {
    int c0 = cg * 4 + p * 32;
    float4 v = *(const float4*)(emb + (size_t)sidx[nl] * C_DIM + c0);
    out[((size_t)bb * C_DIM + c0 + 0) * HWB + hw0 + nl] = v.x;
    out[((size_t)bb * C_DIM + c0 + 1) * HWB + hw0 + nl] = v.y;
    out[((size_t)bb * C_DIM + c0 + 2) * HWB + hw0 + nl] = v.z;
    out[((size_t)bb * C_DIM + c0 + 3) * HWB + hw0 + nl] = v.w;
  }
}

extern "C" void kernel_launch(void* const* d_in, const int* in_sizes, int n_in,
                              void* d_out, int out_size, void* d_ws, size_t ws_size,
                              hipStream_t stream) {
  const float* hid = (const float*)d_in[0];
  const float* emb = (const float*)d_in[1];
  float* out = (float*)d_out;

  float* zt = (float*)d_ws;                        // 8 MB
  float* z2 = zt + (size_t)N_Z * C_DIM;            // 8192
  float* e2 = z2 + N_Z;                            // 8192
  float* cd = e2 + N_EMB;                          // 65536
  int* ci = (int*)(cd + (size_t)NSPLIT * N_Z);     // 65536
  u16* zbf = (u16*)(ci + (size_t)NSPLIT * N_Z);    // 4 MB
  u16* ebf = zbf + (size_t)N_Z * C_DIM;            // 4 MB

  vq_tr<<<2048, 256, 0, stream>>>(hid, zt, zbf);
  vq_norms<<<64, 256, 0, stream>>>(zt, emb, z2, e2, ebf);
  vq_filter<<<(N_Z / MBLK) * NSPLIT, 256, 0, stream>>>(zbf, ebf, zt, emb, z2, e2, cd, ci);
  vq_out<<<N_Z / 32, 256, 0, stream>>>(emb, cd, ci, out);
}